// Round 7
// baseline (83.785 us; speedup 1.0000x reference)
//
#include <hip/hip_runtime.h>

// x[16,64,96,96] f32, dict[100,64,3,3] f32, coeff[256,3,3,3] f32, idx[256,3,3,3] i32
// out[16,256,96,96] f32
#define NB   16
#define CIN  64
#define HH   96
#define WW   96
#define DD   100
#define OO   256
#define NWG  (NB * HH)        // 1536 conv blocks (1 output row each)

typedef __attribute__((ext_vector_type(8))) short  bf16x8;
typedef __attribute__((ext_vector_type(4))) float  f32x4;

// XOR swizzle on the 16B-granule bits (4-6) within a 128B (= one wp) row
#define FSWZ(wp) ((((wp) ^ ((wp) >> 3)) & 7) << 4)

static __device__ __forceinline__ unsigned short f32_to_bf16(float f) {
    unsigned int u = __float_as_uint(f);
    u += 0x7FFFu + ((u >> 16) & 1u);   // RNE
    return (unsigned short)(u >> 16);
}

// ---- prep: W_eff = scatter(coeff,idx) @ dict, MFMA B-fragment lane order.
// halfword index = (kpos*32 + otile*2 + ks)*512 + lane*8 + e
__global__ __launch_bounds__(256) void weff_prep(
    const float* __restrict__ dict, const float* __restrict__ coeff,
    const int* __restrict__ idx, unsigned short* __restrict__ weff2)
{
    __shared__ float wrow[DD];
    const int o = blockIdx.x, tid = threadIdx.x;
    if (tid < DD) wrow[tid] = 0.f;
    __syncthreads();
    if (tid == 0) {                              // deterministic serial scatter
        for (int s = 0; s < 27; ++s) wrow[idx[o * 27 + s]] += coeff[o * 27 + s];
    }
    __syncthreads();
    for (int j = tid; j < 576; j += 256) {       // j = kpos*64 + c
        int kpos = j >> 6, c = j & 63;
        float s = 0.f;
        for (int d = 0; d < DD; ++d)
            s += wrow[d] * dict[d * 576 + c * 9 + kpos];
        int otile = o >> 4, ks = c >> 5;
        int lane8 = (o & 15) | (((c >> 3) & 3) << 4);
        weff2[((size_t)(kpos * 32 + otile * 2 + ks)) * 512 + lane8 * 8 + (c & 7)]
            = f32_to_bf16(s);
    }
}

// ---- conv: block = (b,h) output row; 8 waves 2(w-half) x 4(o-quarter).
// Reads x (f32 NCHW) directly; two-phase in-LDS transpose (conflict-free),
// then 18 unrolled (kpos,ks) half-steps with depth-4 B prefetch.
__global__ __launch_bounds__(512, 4) void conv_kernel(
    const float* __restrict__ x,               // [16][64][96][96] f32
    const unsigned short* __restrict__ weff2,  // fragment-ordered, 288KB
    float* __restrict__ out)                   // [16][256][96][96] f32
{
    __shared__ unsigned short tmp[3 * CIN * 98]; // [r][c][w], stride 98 (bank-spread), 37632 B
    __shared__ unsigned short xs[3 * 98 * 64];   // [r][wp][c] FSWZ fragment buf, 37632 B

    const int wg  = blockIdx.x;
    const int swz = (wg & 7) * (NWG / 8) + (wg >> 3);  // XCD-bijective (1536%8==0)
    const int b = swz / HH, h = swz % HH;
    const int tid = threadIdx.x;
    const int lane = tid & 63, wid = tid >> 6;
    const int wm = wid >> 2, wn = wid & 3;     // wm: w-half, wn: o-quarter

    char* xsb = reinterpret_cast<char*>(xs);

    // ---- B-fragment prologue: banks for steps 0..3 (fly under the transpose) ----
    const unsigned short* wbase = weff2 + (size_t)(wn * 8) * 512 + lane * 8;
    bf16x8 bfr[4][4];
#pragma unroll
    for (int s = 0; s < 4; ++s)
#pragma unroll
        for (int n = 0; n < 4; ++n)
            bfr[s][n] = *reinterpret_cast<const bf16x8*>(
                wbase + (((s >> 1) * 32) + n * 2 + (s & 1)) * 512);

    // ---- phase A: x f32 coalesced -> bf16 -> tmp[r][c][w] (contiguous writes) ----
    const float* xb = x + (size_t)b * CIN * HH * WW;
#pragma unroll
    for (int it = 0; it < 9; ++it) {
        int u = tid + it * 512;                // 3*64*24 = 4608 float4 units
        int r = u / 1536, rem = u % 1536;
        int c = rem / 24, w4 = rem % 24;
        int hp = h - 1 + r;
        float4 v = {0.f, 0.f, 0.f, 0.f};
        if (hp >= 0 && hp < HH)
            v = *reinterpret_cast<const float4*>(xb + ((size_t)c * HH + hp) * WW + w4 * 4);
        unsigned int lo = (unsigned int)f32_to_bf16(v.x) | ((unsigned int)f32_to_bf16(v.y) << 16);
        unsigned int hi = (unsigned int)f32_to_bf16(v.z) | ((unsigned int)f32_to_bf16(v.w) << 16);
        unsigned int* t = reinterpret_cast<unsigned int*>(&tmp[(r * CIN + c) * 98 + w4 * 4]);
        t[0] = lo; t[1] = hi;
    }
    __syncthreads();

    // ---- phase B: gather 8 channels @ fixed w -> bf16x8 -> xs (FSWZ, b128 writes) ----
#pragma unroll
    for (int it = 0; it < 5; ++it) {
        int u = tid + it * 512;                // 3*96*8 = 2304 fragment units
        if (u < 2304) {
            int g = u & 7, q = u >> 3;         // g: c-group, q = r*96 + (wp-1)
            int wpm1 = q % 96, r = q / 96;
            int c0 = g * 8, wp = wpm1 + 1;
            bf16x8 f;
#pragma unroll
            for (int j = 0; j < 8; ++j)
                f[j] = (short)tmp[(r * CIN + c0 + j) * 98 + wpm1];
            *reinterpret_cast<bf16x8*>(
                xsb + r * 12544 + ((wp * 128 + c0 * 2) ^ FSWZ(wp))) = f;
        }
    }
    if (tid < 48) {                            // zero pad wp=0 and wp=97
        int r = tid / 16, side = (tid & 15) >> 3, ci = tid & 7;
        int wp = side ? 97 : 0;
        bf16x8 z = {0,0,0,0,0,0,0,0};
        *reinterpret_cast<bf16x8*>(
            xsb + r * 12544 + ((wp * 128 + ci * 16) ^ FSWZ(wp))) = z;
    }

    f32x4 acc[3][4];
#pragma unroll
    for (int m = 0; m < 3; ++m)
#pragma unroll
        for (int n = 0; n < 4; ++n)
            acc[m][n] = (f32x4){0.f, 0.f, 0.f, 0.f};

    __syncthreads();                           // xs ready

    const int wb16 = wm * 48 + (lane & 15);

    // ---- 18 half-steps: s = (kpos = s>>1, ks = s&1); bank = s&3, prefetch +4 ----
#pragma unroll
    for (int s = 0; s < 18; ++s) {
        const int kpos = s >> 1, ks = s & 1;
        const int kh = kpos / 3, dw = kpos % 3;
        const int cb = (ks * 32 + (lane >> 4) * 8) * 2;   // byte offset of c
        bf16x8 a[3];
#pragma unroll
        for (int m = 0; m < 3; ++m) {
            int wpos = wb16 + m * 16 + dw;
            a[m] = *reinterpret_cast<const bf16x8*>(
                xsb + kh * 12544 + wpos * 128 + (cb ^ FSWZ(wpos)));
        }
#pragma unroll
        for (int m = 0; m < 3; ++m)
#pragma unroll
            for (int n = 0; n < 4; ++n)
                acc[m][n] = __builtin_amdgcn_mfma_f32_16x16x32_bf16(
                    a[m], bfr[s & 3][n], acc[m][n], 0, 0, 0);
        if (s < 14) {                          // reload this bank with step s+4
            const int s4 = s + 4;
            const int off = (s4 >> 1) * 32 + (s4 & 1);
#pragma unroll
            for (int n = 0; n < 4; ++n)
                bfr[s & 3][n] = *reinterpret_cast<const bf16x8*>(
                    wbase + (off + n * 2) * 512);
        }
    }

    // ---- epilogue: plain float4 stores ----
#pragma unroll
    for (int m = 0; m < 3; ++m)
#pragma unroll
        for (int n = 0; n < 4; ++n) {
            int o = wn * 64 + n * 16 + (lane & 15);
            int w = wm * 48 + m * 16 + (lane >> 4) * 4;
            *reinterpret_cast<f32x4*>(
                out + (((size_t)(b * OO + o) * HH + h) * WW + w)) = acc[m][n];
        }
}

extern "C" void kernel_launch(void* const* d_in, const int* in_sizes, int n_in,
                              void* d_out, int out_size, void* d_ws, size_t ws_size,
                              hipStream_t stream) {
    const float* x     = (const float*)d_in[0];
    const float* dict  = (const float*)d_in[1];
    const float* coeff = (const float*)d_in[2];
    const int*   idx   = (const int*)d_in[3];
    float* out = (float*)d_out;

    unsigned short* weff2 = (unsigned short*)d_ws;   // 294912 B

    weff_prep<<<OO, 256, 0, stream>>>(dict, coeff, idx, weff2);
    conv_kernel<<<NWG, 512, 0, stream>>>(x, weff2, out);
}